// Round 1
// baseline (387.962 us; speedup 1.0000x reference)
//
#include <hip/hip_runtime.h>
#include <hip/hip_bf16.h>
#include <math.h>

#define DI __device__ __forceinline__

typedef __attribute__((ext_vector_type(8))) __bf16 bf16x8;
typedef __attribute__((ext_vector_type(8))) short short8;
typedef __attribute__((ext_vector_type(4))) float f32x4;
typedef __attribute__((ext_vector_type(4))) int int4v;
typedef __attribute__((ext_vector_type(4))) unsigned short ushort4v;

DI unsigned short f2bf(float f) {
  union { float f; unsigned u; } v; v.f = f;
  unsigned r = v.u + 0x7fffu + ((v.u >> 16) & 1u);
  return (unsigned short)(r >> 16);
}

DI void gload_lds16(const void* g, void* l) {
  __builtin_amdgcn_global_load_lds(
      (const __attribute__((address_space(1))) void*)g,
      (__attribute__((address_space(3))) void*)l, 16, 0, 0);
}

// ---------------- weight transpose + fp32->bf16 convert ----------------
// out[n][k] = bf16(in[k][n]);  grid = (N/32, K/32), block = 256
__global__ __launch_bounds__(256) void transpose_cvt(
    const float* __restrict__ in, short* __restrict__ out, int K, int N)
{
  __shared__ float tile[32][33];
  const int tx = threadIdx.x & 31, ty = threadIdx.x >> 5;  // ty 0..7
  const int n0 = blockIdx.x * 32, k0 = blockIdx.y * 32;
#pragma unroll
  for (int p = 0; p < 4; ++p)
    tile[ty + p * 8][tx] = in[(size_t)(k0 + ty + p * 8) * N + n0 + tx];
  __syncthreads();
#pragma unroll
  for (int p = 0; p < 4; ++p)
    out[(size_t)(n0 + ty + p * 8) * K + k0 + tx] = (short)f2bf(tile[tx][ty + p * 8]);
}

// ---------------- layernorm: 1 wave per row of 768, fp32 in, bf16 out ----
__global__ __launch_bounds__(256) void ln_rows(
    const float* __restrict__ x, const float* __restrict__ gw,
    const float* __restrict__ bw, unsigned short* __restrict__ out)
{
  const int wv = threadIdx.x >> 6, ln = threadIdx.x & 63;
  const size_t row = (size_t)blockIdx.x * 4 + wv;
  const float* xr = x + row * 768;
  float4 v[3];
  float s = 0.f, sq = 0.f;
#pragma unroll
  for (int i = 0; i < 3; ++i) {
    v[i] = *(const float4*)(xr + i * 256 + ln * 4);
    s  += v[i].x + v[i].y + v[i].z + v[i].w;
    sq += v[i].x * v[i].x + v[i].y * v[i].y + v[i].z * v[i].z + v[i].w * v[i].w;
  }
#pragma unroll
  for (int msk = 1; msk < 64; msk <<= 1) {
    s  += __shfl_xor(s, msk);
    sq += __shfl_xor(sq, msk);
  }
  const float mean = s * (1.f / 768.f);
  const float var  = sq * (1.f / 768.f) - mean * mean;
  const float rstd = rsqrtf(var + 1e-5f);
#pragma unroll
  for (int i = 0; i < 3; ++i) {
    const int c = i * 256 + ln * 4;
    const float vals[4] = {v[i].x, v[i].y, v[i].z, v[i].w};
    ushort4v o;
#pragma unroll
    for (int j = 0; j < 4; ++j)
      o[j] = f2bf((vals[j] - mean) * rstd * gw[c + j] + bw[c + j]);
    *(ushort4v*)(out + row * 768 + c) = o;
  }
}

// ---------------- GEMM: C[M,N] = A[M,K](bf16) * Bt[N,K](bf16)^T + epilogue --
enum { EPI_BF16 = 0, EPI_F32_RES = 1, EPI_BF16_GELU = 2, EPI_F32 = 3 };

template <int MODE>
__global__ __launch_bounds__(256, 2) void gemm_bt(
    const short* __restrict__ A,    // pitch = K
    const short* __restrict__ Bt,   // pitch = K
    const float* __restrict__ bias,
    const float* __restrict__ resid,  // pitch = ldc (fp32) when used
    void* __restrict__ Cout, int ldc,
    int Ntiles, int K)
{
  __shared__ short As[128 * 32];
  __shared__ short Bs[128 * 32];
  const int t = threadIdx.x;
  const int wv = t >> 6, ln = t & 63;
  const int g = ln >> 4, r = ln & 15;
  const int bm = blockIdx.x / Ntiles, bn = blockIdx.x % Ntiles;
  const int wr = wv >> 1, wc = wv & 1;
  f32x4 acc[4][4] = {};

  const int srow = t >> 2;         // 0..63
  const int scol = (t & 3) * 16;   // byte offset within 64B k-slice

  for (int kt = 0; kt < K; kt += 32) {
    const char* a0 = (const char*)(A + (size_t)(bm * 128 + srow) * K + kt) + scol;
    const char* a1 = (const char*)(A + (size_t)(bm * 128 + 64 + srow) * K + kt) + scol;
    const char* b0 = (const char*)(Bt + (size_t)(bn * 128 + srow) * K + kt) + scol;
    const char* b1 = (const char*)(Bt + (size_t)(bn * 128 + 64 + srow) * K + kt) + scol;
    gload_lds16(a0, (char*)As + (size_t)(wv * 64) * 16);
    gload_lds16(a1, (char*)As + (size_t)(256 + wv * 64) * 16);
    gload_lds16(b0, (char*)Bs + (size_t)(wv * 64) * 16);
    gload_lds16(b1, (char*)Bs + (size_t)(256 + wv * 64) * 16);
    __syncthreads();
    bf16x8 af[4], bfr[4];
#pragma unroll
    for (int m = 0; m < 4; ++m)
      af[m] = *(const bf16x8*)(As + (wr * 64 + m * 16 + r) * 32 + g * 8);
#pragma unroll
    for (int n = 0; n < 4; ++n)
      bfr[n] = *(const bf16x8*)(Bs + (wc * 64 + n * 16 + r) * 32 + g * 8);
#pragma unroll
    for (int m = 0; m < 4; ++m)
#pragma unroll
      for (int n = 0; n < 4; ++n)
        acc[m][n] = __builtin_amdgcn_mfma_f32_16x16x32_bf16(af[m], bfr[n], acc[m][n], 0, 0, 0);
    __syncthreads();
  }

  const int colbase = bn * 128 + wc * 64 + r;
  const int rowbase = bm * 128 + wr * 64 + g * 4;
#pragma unroll
  for (int n = 0; n < 4; ++n) {
    const int col = colbase + n * 16;
    const float bv = bias[col];
#pragma unroll
    for (int m = 0; m < 4; ++m) {
#pragma unroll
      for (int q = 0; q < 4; ++q) {
        const size_t row = (size_t)(rowbase + m * 16 + q);
        float v = acc[m][n][q] + bv;
        if constexpr (MODE == EPI_F32_RES) {
          v += resid[row * ldc + col];
          ((float*)Cout)[row * ldc + col] = v;
        } else if constexpr (MODE == EPI_F32) {
          ((float*)Cout)[row * ldc + col] = v;
        } else if constexpr (MODE == EPI_BF16_GELU) {
          v = 0.5f * v * (1.0f + erff(v * 0.70710678118654752f));
          ((unsigned short*)Cout)[row * ldc + col] = f2bf(v);
        } else {
          ((unsigned short*)Cout)[row * ldc + col] = f2bf(v);
        }
      }
    }
  }
}

// ---------------- flash attention ---------------------------------------
// qkv: [8192][2304] bf16 (q|k|v, 768 each; head h at cols h*96..h*96+95)
// out ab: [8192][768] bf16.  softmax(QK^T) * 96 @ V  (no pre-softmax scale)
__global__ __launch_bounds__(256, 2) void attn_fwd(
    const short* __restrict__ qkv, unsigned short* __restrict__ ab)
{
  constexpr int LK = 104, LV = 72, LP = 72;
  __shared__ short Ks[64 * LK];
  __shared__ short Vs[96 * LV];
  __shared__ short Ps[4][16 * LP];
  const int t = threadIdx.x, wv = t >> 6, ln = t & 63;
  const int g = ln >> 4, r = ln & 15;
  const int bh = blockIdx.x >> 4, qt = blockIdx.x & 15;
  const int b = bh >> 3, h = bh & 7;

  // per-wave Q fragments (16 q-rows x 96 d) held in registers
  const size_t rowq = (size_t)(b * 1024 + qt * 64 + wv * 16 + r);
  bf16x8 qf[3];
#pragma unroll
  for (int kd = 0; kd < 3; ++kd)
    qf[kd] = *(const bf16x8*)(qkv + rowq * 2304 + h * 96 + kd * 32 + g * 8);

  f32x4 o[6] = {};
  float mrow[4], lrow[4];
#pragma unroll
  for (int q = 0; q < 4; ++q) { mrow[q] = -1e30f; lrow[q] = 0.f; }

  for (int kt = 0; kt < 16; ++kt) {
    __syncthreads();  // prior PV done reading Ks/Vs
    // stage K [64][96] linear(padded) and V transposed [96][64](padded)
#pragma unroll
    for (int i = 0; i < 3; ++i) {
      const int c = i * 256 + t;                 // 0..767 chunks of 16B
      const int krow = c / 12, cb = c % 12;
      const size_t grow = (size_t)(b * 1024 + kt * 64 + krow) * 2304;
      *(int4v*)(Ks + krow * LK + cb * 8) =
          *(const int4v*)(qkv + grow + 768 + h * 96 + cb * 8);
      const short8 vvv = *(const short8*)(qkv + grow + 1536 + h * 96 + cb * 8);
#pragma unroll
      for (int j = 0; j < 8; ++j)
        Vs[(cb * 8 + j) * LV + krow] = vvv[j];
    }
    __syncthreads();

    // S = Q K^T : 16 x 64 per wave
    f32x4 s[4];
#pragma unroll
    for (int sub = 0; sub < 4; ++sub) {
      f32x4 a = {0.f, 0.f, 0.f, 0.f};
#pragma unroll
      for (int kd = 0; kd < 3; ++kd) {
        bf16x8 kf = *(const bf16x8*)(Ks + (sub * 16 + r) * LK + kd * 32 + g * 8);
        a = __builtin_amdgcn_mfma_f32_16x16x32_bf16(qf[kd], kf, a, 0, 0, 0);
      }
      s[sub] = a;
    }

    // online softmax (row = g*4+q, spread over 16 lanes of same g)
    float mnew[4], scale[4], tsum[4];
#pragma unroll
    for (int q = 0; q < 4; ++q) {
      float tm = s[0][q];
#pragma unroll
      for (int sub = 1; sub < 4; ++sub) tm = fmaxf(tm, s[sub][q]);
#pragma unroll
      for (int msk = 1; msk < 16; msk <<= 1) tm = fmaxf(tm, __shfl_xor(tm, msk));
      mnew[q] = fmaxf(mrow[q], tm);
      scale[q] = __expf(mrow[q] - mnew[q]);
      tsum[q] = 0.f;
    }
#pragma unroll
    for (int sub = 0; sub < 4; ++sub) {
#pragma unroll
      for (int q = 0; q < 4; ++q) {
        const float p = __expf(s[sub][q] - mnew[q]);
        tsum[q] += p;
        Ps[wv][(g * 4 + q) * LP + sub * 16 + r] = (short)f2bf(p);
      }
    }
#pragma unroll
    for (int q = 0; q < 4; ++q) {
#pragma unroll
      for (int msk = 1; msk < 16; msk <<= 1) tsum[q] += __shfl_xor(tsum[q], msk);
      lrow[q] = lrow[q] * scale[q] + tsum[q];
      mrow[q] = mnew[q];
    }
#pragma unroll
    for (int nd = 0; nd < 6; ++nd)
#pragma unroll
      for (int q = 0; q < 4; ++q) o[nd][q] *= scale[q];
    __syncthreads();  // P visible wave-wide

    // O += P V
#pragma unroll
    for (int nd = 0; nd < 6; ++nd) {
#pragma unroll
      for (int kk = 0; kk < 2; ++kk) {
        bf16x8 pf = *(const bf16x8*)(Ps[wv] + r * LP + kk * 32 + g * 8);
        bf16x8 vf = *(const bf16x8*)(Vs + (nd * 16 + r) * LV + kk * 32 + g * 8);
        o[nd] = __builtin_amdgcn_mfma_f32_16x16x32_bf16(pf, vf, o[nd], 0, 0, 0);
      }
    }
  }

  // epilogue: O * (96 / l)
#pragma unroll
  for (int q = 0; q < 4; ++q) {
    const float inv = 96.0f / lrow[q];
    const size_t row = (size_t)(b * 1024 + qt * 64 + wv * 16 + g * 4 + q);
#pragma unroll
    for (int nd = 0; nd < 6; ++nd)
      ab[row * 768 + h * 96 + nd * 16 + r] = f2bf(o[nd][q] * inv);
  }
}

// ------------------------------------------------------------------------
extern "C" void kernel_launch(void* const* d_in, const int* in_sizes, int n_in,
                              void* d_out, int out_size, void* d_ws, size_t ws_size,
                              hipStream_t stream)
{
  const float* x    = (const float*)d_in[0];
  const float* ln1g = (const float*)d_in[1];
  const float* ln1b = (const float*)d_in[2];
  const float* Wq   = (const float*)d_in[3];
  const float* bq   = (const float*)d_in[4];
  const float* Wk   = (const float*)d_in[5];
  const float* bk   = (const float*)d_in[6];
  const float* Wv   = (const float*)d_in[7];
  const float* bv   = (const float*)d_in[8];
  const float* Wo   = (const float*)d_in[9];
  const float* bo   = (const float*)d_in[10];
  const float* ln2g = (const float*)d_in[11];
  const float* ln2b = (const float*)d_in[12];
  const float* W1   = (const float*)d_in[13];
  const float* b1   = (const float*)d_in[14];
  const float* W2   = (const float*)d_in[15];
  const float* b2   = (const float*)d_in[16];

  char* ws = (char*)d_ws;
  size_t off = 0;
  short* Wtqkv = (short*)(ws + off); off += (size_t)2304 * 768 * 2;
  short* Wto   = (short*)(ws + off); off += (size_t)768 * 768 * 2;
  short* Wt1   = (short*)(ws + off); off += (size_t)3072 * 768 * 2;
  short* Wt2   = (short*)(ws + off); off += (size_t)768 * 3072 * 2;
  float* bqkv  = (float*)(ws + off); off += 16384;
  short* hb    = (short*)(ws + off); off += (size_t)8192 * 768 * 2;   // also ab; f1 starts here
  short* qkv   = (short*)(ws + off); off += (size_t)8192 * 2304 * 2;
  short* h2b   = (short*)(ws + off); off += (size_t)8192 * 768 * 2;
  short* f1 = hb;          // [8192][3072] bf16, overlays hb+qkv (both dead)
  short* ab = hb;          // attention output overlays hb (dead after QKV gemm)
  float* x1 = (float*)d_out;  // residual stream parked in d_out (dead before FFN2)

  // weights: transpose to [n][k] bf16
  transpose_cvt<<<dim3(24, 24), 256, 0, stream>>>(Wq, Wtqkv, 768, 768);
  transpose_cvt<<<dim3(24, 24), 256, 0, stream>>>(Wk, Wtqkv + (size_t)768 * 768, 768, 768);
  transpose_cvt<<<dim3(24, 24), 256, 0, stream>>>(Wv, Wtqkv + (size_t)1536 * 768, 768, 768);
  transpose_cvt<<<dim3(24, 24), 256, 0, stream>>>(Wo, Wto, 768, 768);
  transpose_cvt<<<dim3(96, 24), 256, 0, stream>>>(W1, Wt1, 768, 3072);
  transpose_cvt<<<dim3(24, 96), 256, 0, stream>>>(W2, Wt2, 3072, 768);
  hipMemcpyAsync(bqkv,        bq, 768 * sizeof(float), hipMemcpyDeviceToDevice, stream);
  hipMemcpyAsync(bqkv + 768,  bk, 768 * sizeof(float), hipMemcpyDeviceToDevice, stream);
  hipMemcpyAsync(bqkv + 1536, bv, 768 * sizeof(float), hipMemcpyDeviceToDevice, stream);

  // LN1 -> fused QKV gemm -> attention -> O-proj(+bias+residual)
  ln_rows<<<2048, 256, 0, stream>>>(x, ln1g, ln1b, (unsigned short*)hb);
  gemm_bt<EPI_BF16><<<64 * 18, 256, 0, stream>>>(hb, Wtqkv, bqkv, nullptr, qkv, 2304, 18, 768);
  attn_fwd<<<1024, 256, 0, stream>>>(qkv, (unsigned short*)ab);
  gemm_bt<EPI_F32_RES><<<64 * 6, 256, 0, stream>>>(ab, Wto, bo, x, x1, 768, 6, 768);

  // LN2 -> FFN1(+GELU) -> FFN2
  ln_rows<<<2048, 256, 0, stream>>>(x1, ln2g, ln2b, (unsigned short*)h2b);
  gemm_bt<EPI_BF16_GELU><<<64 * 24, 256, 0, stream>>>(h2b, Wt1, b1, nullptr, f1, 3072, 24, 768);
  gemm_bt<EPI_F32><<<64 * 6, 256, 0, stream>>>(f1, Wt2, b2, nullptr, (float*)d_out, 768, 6, 3072);
}

// Round 2
// 336.096 us; speedup vs baseline: 1.1543x; 1.1543x over previous
//
#include <hip/hip_runtime.h>
#include <hip/hip_bf16.h>
#include <math.h>

#define DI __device__ __forceinline__

typedef __attribute__((ext_vector_type(8))) __bf16 bf16x8;
typedef __attribute__((ext_vector_type(8))) short short8;
typedef __attribute__((ext_vector_type(4))) float f32x4;
typedef __attribute__((ext_vector_type(4))) int int4v;
typedef __attribute__((ext_vector_type(4))) unsigned short ushort4v;

DI unsigned short f2bf(float f) {
  union { float f; unsigned u; } v; v.f = f;
  unsigned r = v.u + 0x7fffu + ((v.u >> 16) & 1u);
  return (unsigned short)(r >> 16);
}

DI void gload_lds16(const void* g, void* l) {
  __builtin_amdgcn_global_load_lds(
      (const __attribute__((address_space(1))) void*)g,
      (__attribute__((address_space(3))) void*)l, 16, 0, 0);
}

// ---------------- weight transpose + fp32->bf16 convert ----------------
// out[n][k] = bf16(in[k][n]);  grid = (N/32, K/32), block = 256
__global__ __launch_bounds__(256) void transpose_cvt(
    const float* __restrict__ in, short* __restrict__ out, int K, int N)
{
  __shared__ float tile[32][33];
  const int tx = threadIdx.x & 31, ty = threadIdx.x >> 5;  // ty 0..7
  const int n0 = blockIdx.x * 32, k0 = blockIdx.y * 32;
#pragma unroll
  for (int p = 0; p < 4; ++p)
    tile[ty + p * 8][tx] = in[(size_t)(k0 + ty + p * 8) * N + n0 + tx];
  __syncthreads();
#pragma unroll
  for (int p = 0; p < 4; ++p)
    out[(size_t)(n0 + ty + p * 8) * K + k0 + tx] = (short)f2bf(tile[tx][ty + p * 8]);
}

// ---------------- V transpose: vT[(b*8+h)*96 + d][n] = V[b][n][h*96+d] ----
// qkv: [8192][2304] bf16, V at cols 1536..2303. grid (64 bh, 16 ntile), 256 thr
__global__ __launch_bounds__(256) void v_transpose(
    const short* __restrict__ qkv, short* __restrict__ vT)
{
  __shared__ short tile[64][98];   // 64 n-rows x 96 d-cols (+2 pad, odd dword stride)
  const int t = threadIdx.x;
  const int bh = blockIdx.x, nt = blockIdx.y;
  const int b = bh >> 3, h = bh & 7;
  const size_t gbase = (size_t)(b * 1024 + nt * 64) * 2304 + 1536 + h * 96;
#pragma unroll
  for (int i = 0; i < 3; ++i) {
    const int p = i * 256 + t;
    const int row = p / 12, cb = p % 12;
    const short8 v = *(const short8*)(qkv + gbase + (size_t)row * 2304 + cb * 8);
#pragma unroll
    for (int j = 0; j < 4; ++j) {
      unsigned pk = (unsigned)(unsigned short)v[2 * j] |
                    ((unsigned)(unsigned short)v[2 * j + 1] << 16);
      *(unsigned*)&tile[row][cb * 8 + 2 * j] = pk;
    }
  }
  __syncthreads();
#pragma unroll
  for (int i = 0; i < 3; ++i) {
    const int p = i * 256 + t;
    const int d = p >> 3, cb = p & 7;
    short8 o;
#pragma unroll
    for (int j = 0; j < 8; ++j) o[j] = tile[cb * 8 + j][d];
    *(short8*)(vT + ((size_t)bh * 96 + d) * 1024 + nt * 64 + cb * 8) = o;
  }
}

// ---------------- layernorm: 1 wave per row of 768, fp32 in, bf16 out ----
__global__ __launch_bounds__(256) void ln_rows(
    const float* __restrict__ x, const float* __restrict__ gw,
    const float* __restrict__ bw, unsigned short* __restrict__ out)
{
  const int wv = threadIdx.x >> 6, ln = threadIdx.x & 63;
  const size_t row = (size_t)blockIdx.x * 4 + wv;
  const float* xr = x + row * 768;
  float4 v[3];
  float s = 0.f, sq = 0.f;
#pragma unroll
  for (int i = 0; i < 3; ++i) {
    v[i] = *(const float4*)(xr + i * 256 + ln * 4);
    s  += v[i].x + v[i].y + v[i].z + v[i].w;
    sq += v[i].x * v[i].x + v[i].y * v[i].y + v[i].z * v[i].z + v[i].w * v[i].w;
  }
#pragma unroll
  for (int msk = 1; msk < 64; msk <<= 1) {
    s  += __shfl_xor(s, msk);
    sq += __shfl_xor(sq, msk);
  }
  const float mean = s * (1.f / 768.f);
  const float var  = sq * (1.f / 768.f) - mean * mean;
  const float rstd = rsqrtf(var + 1e-5f);
#pragma unroll
  for (int i = 0; i < 3; ++i) {
    const int c = i * 256 + ln * 4;
    const float vals[4] = {v[i].x, v[i].y, v[i].z, v[i].w};
    ushort4v o;
#pragma unroll
    for (int j = 0; j < 4; ++j)
      o[j] = f2bf((vals[j] - mean) * rstd * gw[c + j] + bw[c + j]);
    *(ushort4v*)(out + row * 768 + c) = o;
  }
}

// ---------------- GEMM: C[M,N] = A[M,K](bf16) * Bt[N,K](bf16)^T + epilogue --
enum { EPI_BF16 = 0, EPI_F32_RES = 1, EPI_BF16_GELU = 2, EPI_F32 = 3 };

template <int MODE>
__global__ __launch_bounds__(256, 2) void gemm_bt(
    const short* __restrict__ A,    // pitch = K
    const short* __restrict__ Bt,   // pitch = K
    const float* __restrict__ bias,
    const float* __restrict__ resid,  // pitch = ldc (fp32) when used
    void* __restrict__ Cout, int ldc,
    int Ntiles, int K)
{
  __shared__ short As[128 * 32];
  __shared__ short Bs[128 * 32];
  const int t = threadIdx.x;
  const int wv = t >> 6, ln = t & 63;
  const int g = ln >> 4, r = ln & 15;
  const int bm = blockIdx.x / Ntiles, bn = blockIdx.x % Ntiles;
  const int wr = wv >> 1, wc = wv & 1;
  f32x4 acc[4][4] = {};

  const int srow = t >> 2;         // 0..63
  const int scol = (t & 3) * 16;   // byte offset within 64B k-slice

  for (int kt = 0; kt < K; kt += 32) {
    const char* a0 = (const char*)(A + (size_t)(bm * 128 + srow) * K + kt) + scol;
    const char* a1 = (const char*)(A + (size_t)(bm * 128 + 64 + srow) * K + kt) + scol;
    const char* b0 = (const char*)(Bt + (size_t)(bn * 128 + srow) * K + kt) + scol;
    const char* b1 = (const char*)(Bt + (size_t)(bn * 128 + 64 + srow) * K + kt) + scol;
    gload_lds16(a0, (char*)As + (size_t)(wv * 64) * 16);
    gload_lds16(a1, (char*)As + (size_t)(256 + wv * 64) * 16);
    gload_lds16(b0, (char*)Bs + (size_t)(wv * 64) * 16);
    gload_lds16(b1, (char*)Bs + (size_t)(256 + wv * 64) * 16);
    __syncthreads();
    bf16x8 af[4], bfr[4];
#pragma unroll
    for (int m = 0; m < 4; ++m)
      af[m] = *(const bf16x8*)(As + (wr * 64 + m * 16 + r) * 32 + g * 8);
#pragma unroll
    for (int n = 0; n < 4; ++n)
      bfr[n] = *(const bf16x8*)(Bs + (wc * 64 + n * 16 + r) * 32 + g * 8);
#pragma unroll
    for (int m = 0; m < 4; ++m)
#pragma unroll
      for (int n = 0; n < 4; ++n)
        acc[m][n] = __builtin_amdgcn_mfma_f32_16x16x32_bf16(af[m], bfr[n], acc[m][n], 0, 0, 0);
    __syncthreads();
  }

  const int colbase = bn * 128 + wc * 64 + r;
  const int rowbase = bm * 128 + wr * 64 + g * 4;
#pragma unroll
  for (int n = 0; n < 4; ++n) {
    const int col = colbase + n * 16;
    const float bv = bias[col];
#pragma unroll
    for (int m = 0; m < 4; ++m) {
#pragma unroll
      for (int q = 0; q < 4; ++q) {
        const size_t row = (size_t)(rowbase + m * 16 + q);
        float v = acc[m][n][q] + bv;
        if constexpr (MODE == EPI_F32_RES) {
          v += resid[row * ldc + col];
          ((float*)Cout)[row * ldc + col] = v;
        } else if constexpr (MODE == EPI_F32) {
          ((float*)Cout)[row * ldc + col] = v;
        } else if constexpr (MODE == EPI_BF16_GELU) {
          v = 0.5f * v * (1.0f + erff(v * 0.70710678118654752f));
          ((unsigned short*)Cout)[row * ldc + col] = f2bf(v);
        } else {
          ((unsigned short*)Cout)[row * ldc + col] = f2bf(v);
        }
      }
    }
  }
}

// ---------------- flash attention v2 -------------------------------------
// qkv: [8192][2304] bf16 (q|k|v). vT: [(b*8+h)*96 + d][1024] bf16.
// out ab: [8192][768] bf16.  softmax(QK^T) * 96 @ V  (no pre-softmax scale)
// K staged [64][128] (cols 0..95 data), V^T staged [96][64]; both XOR-swizzled
// per 16B chunk: phys_chunk = logical_chunk ^ (row & 7), applied on the
// global SOURCE at stage time and on the LDS address at read time (rule #21).
__global__ __launch_bounds__(256, 2) void attn_fwd(
    const short* __restrict__ qkv, const short* __restrict__ vT,
    unsigned short* __restrict__ ab)
{
  constexpr int LP = 72;
  __shared__ short Ks[64 * 128];   // 16 KB
  __shared__ short Vs[96 * 64];    // 12 KB
  __shared__ short Ps[4][16 * LP]; //  9 KB
  const int t = threadIdx.x, wv = t >> 6, ln = t & 63;
  const int g = ln >> 4, r = ln & 15;
  const int bh = blockIdx.x >> 4, qt = blockIdx.x & 15;
  const int b = bh >> 3, h = bh & 7;

  // per-wave Q fragments (16 q-rows x 96 d) held in registers
  const size_t rowq = (size_t)(b * 1024 + qt * 64 + wv * 16 + r);
  bf16x8 qf[3];
#pragma unroll
  for (int kd = 0; kd < 3; ++kd)
    qf[kd] = *(const bf16x8*)(qkv + rowq * 2304 + h * 96 + kd * 32 + g * 8);

  // staging source offsets (pre-swizzled), constant across kt
  size_t offK[4];
#pragma unroll
  for (int i = 0; i < 4; ++i) {
    const int p = i * 256 + t;
    const int row = p >> 4, cb = p & 15, cbs = cb ^ (row & 7);
    offK[i] = (size_t)row * 2304 + 768 + h * 96 + (cbs << 3);
  }
  size_t offV[3];
#pragma unroll
  for (int i = 0; i < 3; ++i) {
    const int p = i * 256 + t;
    const int row = p >> 3, cb = p & 7, cbs = cb ^ (row & 7);
    offV[i] = ((size_t)bh * 96 + row) * 1024 + (cbs << 3);
  }
  const short* qb = qkv + (size_t)b * 1024 * 2304;

  f32x4 o[6] = {};
  float mrow[4], lrow[4];
#pragma unroll
  for (int q = 0; q < 4; ++q) { mrow[q] = -1e30f; lrow[q] = 0.f; }

  for (int kt = 0; kt < 16; ++kt) {
    __syncthreads();  // prior QK/PV done reading Ks/Vs
    const size_t kadd = (size_t)kt * 64 * 2304;
#pragma unroll
    for (int i = 0; i < 4; ++i)
      gload_lds16(qb + kadd + offK[i], (char*)Ks + i * 4096 + wv * 1024);
#pragma unroll
    for (int i = 0; i < 3; ++i)
      gload_lds16(vT + offV[i] + kt * 64, (char*)Vs + i * 4096 + wv * 1024);
    __syncthreads();

    // S = Q K^T : 16 x 64 per wave (swizzled K reads)
    f32x4 s[4];
#pragma unroll
    for (int sub = 0; sub < 4; ++sub) {
      f32x4 a = {0.f, 0.f, 0.f, 0.f};
#pragma unroll
      for (int kd = 0; kd < 3; ++kd) {
        const bf16x8 kf = *(const bf16x8*)(
            Ks + (sub * 16 + r) * 128 + (((kd * 4 + g) ^ (r & 7)) << 3));
        a = __builtin_amdgcn_mfma_f32_16x16x32_bf16(qf[kd], kf, a, 0, 0, 0);
      }
      s[sub] = a;
    }

    // online softmax (row = g*4+q, spread over 16 lanes of same g)
    float mnew[4], scale[4], tsum[4];
#pragma unroll
    for (int q = 0; q < 4; ++q) {
      float tm = s[0][q];
#pragma unroll
      for (int sub = 1; sub < 4; ++sub) tm = fmaxf(tm, s[sub][q]);
#pragma unroll
      for (int msk = 1; msk < 16; msk <<= 1) tm = fmaxf(tm, __shfl_xor(tm, msk));
      mnew[q] = fmaxf(mrow[q], tm);
      scale[q] = __expf(mrow[q] - mnew[q]);
      tsum[q] = 0.f;
    }
#pragma unroll
    for (int sub = 0; sub < 4; ++sub) {
#pragma unroll
      for (int q = 0; q < 4; ++q) {
        const float p = __expf(s[sub][q] - mnew[q]);
        tsum[q] += p;
        Ps[wv][(g * 4 + q) * LP + sub * 16 + r] = (short)f2bf(p);
      }
    }
#pragma unroll
    for (int q = 0; q < 4; ++q) {
#pragma unroll
      for (int msk = 1; msk < 16; msk <<= 1) tsum[q] += __shfl_xor(tsum[q], msk);
      lrow[q] = lrow[q] * scale[q] + tsum[q];
      mrow[q] = mnew[q];
    }
#pragma unroll
    for (int nd = 0; nd < 6; ++nd)
#pragma unroll
      for (int q = 0; q < 4; ++q) o[nd][q] *= scale[q];
    // P is wave-private (Ps[wv]) — no barrier needed before PV.

    // O += P V  (swizzled V^T reads)
#pragma unroll
    for (int nd = 0; nd < 6; ++nd) {
#pragma unroll
      for (int kk = 0; kk < 2; ++kk) {
        const bf16x8 pf = *(const bf16x8*)(Ps[wv] + r * LP + kk * 32 + g * 8);
        const bf16x8 vf = *(const bf16x8*)(
            Vs + (nd * 16 + r) * 64 + (((kk * 4 + g) ^ (r & 7)) << 3));
        o[nd] = __builtin_amdgcn_mfma_f32_16x16x32_bf16(pf, vf, o[nd], 0, 0, 0);
      }
    }
  }

  // epilogue: O * (96 / l)
#pragma unroll
  for (int q = 0; q < 4; ++q) {
    const float inv = 96.0f / lrow[q];
    const size_t row = (size_t)(b * 1024 + qt * 64 + wv * 16 + g * 4 + q);
#pragma unroll
    for (int nd = 0; nd < 6; ++nd)
      ab[row * 768 + h * 96 + nd * 16 + r] = f2bf(o[nd][q] * inv);
  }
}

// ------------------------------------------------------------------------
extern "C" void kernel_launch(void* const* d_in, const int* in_sizes, int n_in,
                              void* d_out, int out_size, void* d_ws, size_t ws_size,
                              hipStream_t stream)
{
  const float* x    = (const float*)d_in[0];
  const float* ln1g = (const float*)d_in[1];
  const float* ln1b = (const float*)d_in[2];
  const float* Wq   = (const float*)d_in[3];
  const float* bq   = (const float*)d_in[4];
  const float* Wk   = (const float*)d_in[5];
  const float* bk   = (const float*)d_in[6];
  const float* Wv   = (const float*)d_in[7];
  const float* bv   = (const float*)d_in[8];
  const float* Wo   = (const float*)d_in[9];
  const float* bo   = (const float*)d_in[10];
  const float* ln2g = (const float*)d_in[11];
  const float* ln2b = (const float*)d_in[12];
  const float* W1   = (const float*)d_in[13];
  const float* b1   = (const float*)d_in[14];
  const float* W2   = (const float*)d_in[15];
  const float* b2   = (const float*)d_in[16];

  char* ws = (char*)d_ws;
  size_t off = 0;
  short* Wtqkv = (short*)(ws + off); off += (size_t)2304 * 768 * 2;
  short* Wto   = (short*)(ws + off); off += (size_t)768 * 768 * 2;
  short* Wt1   = (short*)(ws + off); off += (size_t)3072 * 768 * 2;
  short* Wt2   = (short*)(ws + off); off += (size_t)768 * 3072 * 2;
  float* bqkv  = (float*)(ws + off); off += 16384;
  short* hb    = (short*)(ws + off); off += (size_t)8192 * 768 * 2;   // also ab; f1 starts here
  short* qkv   = (short*)(ws + off); off += (size_t)8192 * 2304 * 2;
  short* h2b   = (short*)(ws + off); off += (size_t)8192 * 768 * 2;
  short* f1 = hb;          // [8192][3072] bf16, overlays hb+qkv (both dead)
  short* ab = hb;          // attention output overlays hb (dead after QKV gemm)
  short* vT = h2b;         // V^T [64*96][1024], overlays h2b (h2b live only after O-proj)
  float* x1 = (float*)d_out;  // residual stream parked in d_out (dead before FFN2)

  // weights: transpose to [n][k] bf16
  transpose_cvt<<<dim3(24, 24), 256, 0, stream>>>(Wq, Wtqkv, 768, 768);
  transpose_cvt<<<dim3(24, 24), 256, 0, stream>>>(Wk, Wtqkv + (size_t)768 * 768, 768, 768);
  transpose_cvt<<<dim3(24, 24), 256, 0, stream>>>(Wv, Wtqkv + (size_t)1536 * 768, 768, 768);
  transpose_cvt<<<dim3(24, 24), 256, 0, stream>>>(Wo, Wto, 768, 768);
  transpose_cvt<<<dim3(96, 24), 256, 0, stream>>>(W1, Wt1, 768, 3072);
  transpose_cvt<<<dim3(24, 96), 256, 0, stream>>>(W2, Wt2, 3072, 768);
  hipMemcpyAsync(bqkv,        bq, 768 * sizeof(float), hipMemcpyDeviceToDevice, stream);
  hipMemcpyAsync(bqkv + 768,  bk, 768 * sizeof(float), hipMemcpyDeviceToDevice, stream);
  hipMemcpyAsync(bqkv + 1536, bv, 768 * sizeof(float), hipMemcpyDeviceToDevice, stream);

  // LN1 -> fused QKV gemm -> V^T -> attention -> O-proj(+bias+residual)
  ln_rows<<<2048, 256, 0, stream>>>(x, ln1g, ln1b, (unsigned short*)hb);
  gemm_bt<EPI_BF16><<<64 * 18, 256, 0, stream>>>(hb, Wtqkv, bqkv, nullptr, qkv, 2304, 18, 768);
  v_transpose<<<dim3(64, 16), 256, 0, stream>>>(qkv, vT);
  attn_fwd<<<1024, 256, 0, stream>>>(qkv, vT, (unsigned short*)ab);
  gemm_bt<EPI_F32_RES><<<64 * 6, 256, 0, stream>>>(ab, Wto, bo, x, x1, 768, 6, 768);

  // LN2 -> FFN1(+GELU) -> FFN2
  ln_rows<<<2048, 256, 0, stream>>>(x1, ln2g, ln2b, (unsigned short*)h2b);
  gemm_bt<EPI_BF16_GELU><<<64 * 24, 256, 0, stream>>>(h2b, Wt1, b1, nullptr, f1, 3072, 24, 768);
  gemm_bt<EPI_F32><<<64 * 6, 256, 0, stream>>>(f1, Wt2, b2, nullptr, (float*)d_out, 768, 6, 3072);
}

// Round 3
// 324.033 us; speedup vs baseline: 1.1973x; 1.0372x over previous
//
#include <hip/hip_runtime.h>
#include <hip/hip_bf16.h>
#include <math.h>

#define DI __device__ __forceinline__

typedef __attribute__((ext_vector_type(8))) __bf16 bf16x8;
typedef __attribute__((ext_vector_type(8))) short short8;
typedef __attribute__((ext_vector_type(4))) float f32x4;
typedef __attribute__((ext_vector_type(4))) int int4v;
typedef __attribute__((ext_vector_type(4))) unsigned short ushort4v;

DI unsigned short f2bf(float f) {
  union { float f; unsigned u; } v; v.f = f;
  unsigned r = v.u + 0x7fffu + ((v.u >> 16) & 1u);
  return (unsigned short)(r >> 16);
}

DI void gload_lds16(const void* g, void* l) {
  __builtin_amdgcn_global_load_lds(
      (const __attribute__((address_space(1))) void*)g,
      (__attribute__((address_space(3))) void*)l, 16, 0, 0);
}

// ---------------- weight transpose + fp32->bf16 convert ----------------
__global__ __launch_bounds__(256) void transpose_cvt(
    const float* __restrict__ in, short* __restrict__ out, int K, int N)
{
  __shared__ float tile[32][33];
  const int tx = threadIdx.x & 31, ty = threadIdx.x >> 5;
  const int n0 = blockIdx.x * 32, k0 = blockIdx.y * 32;
#pragma unroll
  for (int p = 0; p < 4; ++p)
    tile[ty + p * 8][tx] = in[(size_t)(k0 + ty + p * 8) * N + n0 + tx];
  __syncthreads();
#pragma unroll
  for (int p = 0; p < 4; ++p)
    out[(size_t)(n0 + ty + p * 8) * K + k0 + tx] = (short)f2bf(tile[tx][ty + p * 8]);
}

// ---------------- V transpose: vT[(b*8+h)*96 + d][n] = V[b][n][h*96+d] ----
__global__ __launch_bounds__(256) void v_transpose(
    const short* __restrict__ qkv, short* __restrict__ vT)
{
  __shared__ short tile[64][98];
  const int t = threadIdx.x;
  const int bh = blockIdx.x, nt = blockIdx.y;
  const int b = bh >> 3, h = bh & 7;
  const size_t gbase = (size_t)(b * 1024 + nt * 64) * 2304 + 1536 + h * 96;
#pragma unroll
  for (int i = 0; i < 3; ++i) {
    const int p = i * 256 + t;
    const int row = p / 12, cb = p % 12;
    const short8 v = *(const short8*)(qkv + gbase + (size_t)row * 2304 + cb * 8);
#pragma unroll
    for (int j = 0; j < 4; ++j) {
      unsigned pk = (unsigned)(unsigned short)v[2 * j] |
                    ((unsigned)(unsigned short)v[2 * j + 1] << 16);
      *(unsigned*)&tile[row][cb * 8 + 2 * j] = pk;
    }
  }
  __syncthreads();
#pragma unroll
  for (int i = 0; i < 3; ++i) {
    const int p = i * 256 + t;
    const int d = p >> 3, cb = p & 7;
    short8 o;
#pragma unroll
    for (int j = 0; j < 8; ++j) o[j] = tile[cb * 8 + j][d];
    *(short8*)(vT + ((size_t)bh * 96 + d) * 1024 + nt * 64 + cb * 8) = o;
  }
}

// ---------------- layernorm: 1 wave per row of 768, fp32 in, bf16 out ----
__global__ __launch_bounds__(256) void ln_rows(
    const float* __restrict__ x, const float* __restrict__ gw,
    const float* __restrict__ bw, unsigned short* __restrict__ out)
{
  const int wv = threadIdx.x >> 6, ln = threadIdx.x & 63;
  const size_t row = (size_t)blockIdx.x * 4 + wv;
  const float* xr = x + row * 768;
  float4 v[3];
  float s = 0.f, sq = 0.f;
#pragma unroll
  for (int i = 0; i < 3; ++i) {
    v[i] = *(const float4*)(xr + i * 256 + ln * 4);
    s  += v[i].x + v[i].y + v[i].z + v[i].w;
    sq += v[i].x * v[i].x + v[i].y * v[i].y + v[i].z * v[i].z + v[i].w * v[i].w;
  }
#pragma unroll
  for (int msk = 1; msk < 64; msk <<= 1) {
    s  += __shfl_xor(s, msk);
    sq += __shfl_xor(sq, msk);
  }
  const float mean = s * (1.f / 768.f);
  const float var  = sq * (1.f / 768.f) - mean * mean;
  const float rstd = rsqrtf(var + 1e-5f);
#pragma unroll
  for (int i = 0; i < 3; ++i) {
    const int c = i * 256 + ln * 4;
    const float vals[4] = {v[i].x, v[i].y, v[i].z, v[i].w};
    ushort4v o;
#pragma unroll
    for (int j = 0; j < 4; ++j)
      o[j] = f2bf((vals[j] - mean) * rstd * gw[c + j] + bw[c + j]);
    *(ushort4v*)(out + row * 768 + c) = o;
  }
}

// ---------------- GEMM: C[M,N] = A[M,K](bf16) * Bt[N,K](bf16)^T + epilogue --
// Epilogue bounces acc through LDS (pitch-132 fp32) for coalesced stores.
enum { EPI_BF16 = 0, EPI_F32_RES = 1, EPI_BF16_GELU = 2, EPI_F32 = 3 };
#define EPITCH 132

template <int MODE>
__global__ __launch_bounds__(256, 2) void gemm_bt(
    const short* __restrict__ A,    // pitch = K
    const short* __restrict__ Bt,   // pitch = K
    const float* __restrict__ bias,
    const float* __restrict__ resid,  // pitch = ldc (fp32) when used
    void* __restrict__ Cout, int ldc,
    int Ntiles, int K)
{
  __shared__ __align__(16) char smem[32 * EPITCH * 4];  // 16896 B
  short* As = (short*)smem;            // 128x32 bf16 = 8192 B
  short* Bs = (short*)(smem + 8192);   // 8192 B
  const int t = threadIdx.x;
  const int wv = t >> 6, ln = t & 63;
  const int g = ln >> 4, r = ln & 15;
  // XCD-chunked block swizzle (gridDim.x % 8 == 0 for all call sites)
  const int sw = ((int)blockIdx.x & 7) * ((int)gridDim.x >> 3) + ((int)blockIdx.x >> 3);
  const int bm = sw / Ntiles, bn = sw % Ntiles;
  const int wr = wv >> 1, wc = wv & 1;
  f32x4 acc[4][4] = {};

  const int srow = t >> 2;
  const int scol = (t & 3) * 16;

  for (int kt = 0; kt < K; kt += 32) {
    const char* a0 = (const char*)(A + (size_t)(bm * 128 + srow) * K + kt) + scol;
    const char* a1 = (const char*)(A + (size_t)(bm * 128 + 64 + srow) * K + kt) + scol;
    const char* b0 = (const char*)(Bt + (size_t)(bn * 128 + srow) * K + kt) + scol;
    const char* b1 = (const char*)(Bt + (size_t)(bn * 128 + 64 + srow) * K + kt) + scol;
    gload_lds16(a0, (char*)As + (size_t)(wv * 64) * 16);
    gload_lds16(a1, (char*)As + (size_t)(256 + wv * 64) * 16);
    gload_lds16(b0, (char*)Bs + (size_t)(wv * 64) * 16);
    gload_lds16(b1, (char*)Bs + (size_t)(256 + wv * 64) * 16);
    __syncthreads();
    bf16x8 af[4], bfr[4];
#pragma unroll
    for (int m = 0; m < 4; ++m)
      af[m] = *(const bf16x8*)(As + (wr * 64 + m * 16 + r) * 32 + g * 8);
#pragma unroll
    for (int n = 0; n < 4; ++n)
      bfr[n] = *(const bf16x8*)(Bs + (wc * 64 + n * 16 + r) * 32 + g * 8);
#pragma unroll
    for (int m = 0; m < 4; ++m)
#pragma unroll
      for (int n = 0; n < 4; ++n)
        acc[m][n] = __builtin_amdgcn_mfma_f32_16x16x32_bf16(af[m], bfr[n], acc[m][n], 0, 0, 0);
    __syncthreads();
  }

  // ---- epilogue: LDS bounce, coalesced stores ----
  float* epi = (float*)smem;
  const int cq = (t & 7) * 16;         // col offset within tile, this thread
  const int c0 = bn * 128 + cq;        // global col base (16 cols per thread)
  f32x4 bv[4];
#pragma unroll
  for (int j = 0; j < 4; ++j) bv[j] = *(const f32x4*)(bias + c0 + j * 4);

#pragma unroll
  for (int m = 0; m < 4; ++m) {
    // write this m-slab's fragments: local rows wr*16+g*4+q (0..31), cols 0..127
#pragma unroll
    for (int n = 0; n < 4; ++n) {
      const int col = wc * 64 + n * 16 + r;
#pragma unroll
      for (int q = 0; q < 4; ++q)
        epi[(wr * 16 + g * 4 + q) * EPITCH + col] = acc[m][n][q];
    }
    __syncthreads();
    // read back: thread t handles LDS row t>>3, 16 cols at cq
    const int lr = t >> 3;
    const size_t grow = (size_t)(bm * 128 + (lr < 16 ? m * 16 + lr : 48 + m * 16 + lr));
    float vals[16];
#pragma unroll
    for (int j = 0; j < 4; ++j) {
      const f32x4 vv = *(const f32x4*)(epi + lr * EPITCH + cq + j * 4);
#pragma unroll
      for (int e = 0; e < 4; ++e) vals[j * 4 + e] = vv[e] + bv[j][e];
    }
    if constexpr (MODE == EPI_F32_RES) {
#pragma unroll
      for (int j = 0; j < 4; ++j) {
        const f32x4 rv = *(const f32x4*)(resid + grow * ldc + c0 + j * 4);
#pragma unroll
        for (int e = 0; e < 4; ++e) vals[j * 4 + e] += rv[e];
      }
    }
    if constexpr (MODE == EPI_BF16_GELU) {
#pragma unroll
      for (int j = 0; j < 16; ++j)
        vals[j] = 0.5f * vals[j] * (1.0f + erff(vals[j] * 0.70710678118654752f));
    }
    if constexpr (MODE == EPI_F32 || MODE == EPI_F32_RES) {
      float* op = (float*)Cout + grow * ldc + c0;
#pragma unroll
      for (int j = 0; j < 4; ++j) {
        f32x4 ov;
#pragma unroll
        for (int e = 0; e < 4; ++e) ov[e] = vals[j * 4 + e];
        *(f32x4*)(op + j * 4) = ov;
      }
    } else {
      unsigned short* op = (unsigned short*)Cout + grow * ldc + c0;
#pragma unroll
      for (int hhalf = 0; hhalf < 2; ++hhalf) {
        short8 ov;
#pragma unroll
        for (int e = 0; e < 8; ++e) ov[e] = (short)f2bf(vals[hhalf * 8 + e]);
        *(short8*)(op + hhalf * 8) = ov;
      }
    }
    __syncthreads();  // protect epi before next m overwrites
  }
}

// ---------------- flash attention v2 -------------------------------------
__global__ __launch_bounds__(256, 2) void attn_fwd(
    const short* __restrict__ qkv, const short* __restrict__ vT,
    unsigned short* __restrict__ ab)
{
  constexpr int LP = 72;
  __shared__ short Ks[64 * 128];
  __shared__ short Vs[96 * 64];
  __shared__ short Ps[4][16 * LP];
  const int t = threadIdx.x, wv = t >> 6, ln = t & 63;
  const int g = ln >> 4, r = ln & 15;
  // XCD-chunked swizzle: 16 consecutive blocks share (b,h) K/V panels
  const int bid = ((int)blockIdx.x & 7) * 128 + ((int)blockIdx.x >> 3);
  const int bh = bid >> 4, qt = bid & 15;
  const int b = bh >> 3, h = bh & 7;

  const size_t rowq = (size_t)(b * 1024 + qt * 64 + wv * 16 + r);
  bf16x8 qf[3];
#pragma unroll
  for (int kd = 0; kd < 3; ++kd)
    qf[kd] = *(const bf16x8*)(qkv + rowq * 2304 + h * 96 + kd * 32 + g * 8);

  size_t offK[4];
#pragma unroll
  for (int i = 0; i < 4; ++i) {
    const int p = i * 256 + t;
    const int row = p >> 4, cb = p & 15, cbs = cb ^ (row & 7);
    offK[i] = (size_t)row * 2304 + 768 + h * 96 + (cbs << 3);
  }
  size_t offV[3];
#pragma unroll
  for (int i = 0; i < 3; ++i) {
    const int p = i * 256 + t;
    const int row = p >> 3, cb = p & 7, cbs = cb ^ (row & 7);
    offV[i] = ((size_t)bh * 96 + row) * 1024 + (cbs << 3);
  }
  const short* qb = qkv + (size_t)b * 1024 * 2304;

  f32x4 o[6] = {};
  float mrow[4], lrow[4];
#pragma unroll
  for (int q = 0; q < 4; ++q) { mrow[q] = -1e30f; lrow[q] = 0.f; }

  for (int kt = 0; kt < 16; ++kt) {
    __syncthreads();
    const size_t kadd = (size_t)kt * 64 * 2304;
#pragma unroll
    for (int i = 0; i < 4; ++i)
      gload_lds16(qb + kadd + offK[i], (char*)Ks + i * 4096 + wv * 1024);
#pragma unroll
    for (int i = 0; i < 3; ++i)
      gload_lds16(vT + offV[i] + kt * 64, (char*)Vs + i * 4096 + wv * 1024);
    __syncthreads();

    f32x4 s[4];
    __builtin_amdgcn_s_setprio(1);
#pragma unroll
    for (int sub = 0; sub < 4; ++sub) {
      f32x4 a = {0.f, 0.f, 0.f, 0.f};
#pragma unroll
      for (int kd = 0; kd < 3; ++kd) {
        const bf16x8 kf = *(const bf16x8*)(
            Ks + (sub * 16 + r) * 128 + (((kd * 4 + g) ^ (r & 7)) << 3));
        a = __builtin_amdgcn_mfma_f32_16x16x32_bf16(qf[kd], kf, a, 0, 0, 0);
      }
      s[sub] = a;
    }
    __builtin_amdgcn_s_setprio(0);

    float mnew[4], scale[4], tsum[4];
#pragma unroll
    for (int q = 0; q < 4; ++q) {
      float tm = s[0][q];
#pragma unroll
      for (int sub = 1; sub < 4; ++sub) tm = fmaxf(tm, s[sub][q]);
#pragma unroll
      for (int msk = 1; msk < 16; msk <<= 1) tm = fmaxf(tm, __shfl_xor(tm, msk));
      mnew[q] = fmaxf(mrow[q], tm);
      scale[q] = __expf(mrow[q] - mnew[q]);
      tsum[q] = 0.f;
    }
#pragma unroll
    for (int sub = 0; sub < 4; ++sub) {
#pragma unroll
      for (int q = 0; q < 4; ++q) {
        const float p = __expf(s[sub][q] - mnew[q]);
        tsum[q] += p;
        Ps[wv][(g * 4 + q) * LP + sub * 16 + r] = (short)f2bf(p);
      }
    }
#pragma unroll
    for (int q = 0; q < 4; ++q) {
#pragma unroll
      for (int msk = 1; msk < 16; msk <<= 1) tsum[q] += __shfl_xor(tsum[q], msk);
      lrow[q] = lrow[q] * scale[q] + tsum[q];
      mrow[q] = mnew[q];
    }
#pragma unroll
    for (int nd = 0; nd < 6; ++nd)
#pragma unroll
      for (int q = 0; q < 4; ++q) o[nd][q] *= scale[q];

    __builtin_amdgcn_s_setprio(1);
#pragma unroll
    for (int nd = 0; nd < 6; ++nd) {
#pragma unroll
      for (int kk = 0; kk < 2; ++kk) {
        const bf16x8 pf = *(const bf16x8*)(Ps[wv] + r * LP + kk * 32 + g * 8);
        const bf16x8 vf = *(const bf16x8*)(
            Vs + (nd * 16 + r) * 64 + (((kk * 4 + g) ^ (r & 7)) << 3));
        o[nd] = __builtin_amdgcn_mfma_f32_16x16x32_bf16(pf, vf, o[nd], 0, 0, 0);
      }
    }
    __builtin_amdgcn_s_setprio(0);
  }

#pragma unroll
  for (int q = 0; q < 4; ++q) {
    const float inv = 96.0f / lrow[q];
    const size_t row = (size_t)(b * 1024 + qt * 64 + wv * 16 + g * 4 + q);
#pragma unroll
    for (int nd = 0; nd < 6; ++nd)
      ab[row * 768 + h * 96 + nd * 16 + r] = f2bf(o[nd][q] * inv);
  }
}

// ------------------------------------------------------------------------
extern "C" void kernel_launch(void* const* d_in, const int* in_sizes, int n_in,
                              void* d_out, int out_size, void* d_ws, size_t ws_size,
                              hipStream_t stream)
{
  const float* x    = (const float*)d_in[0];
  const float* ln1g = (const float*)d_in[1];
  const float* ln1b = (const float*)d_in[2];
  const float* Wq   = (const float*)d_in[3];
  const float* bq   = (const float*)d_in[4];
  const float* Wk   = (const float*)d_in[5];
  const float* bk   = (const float*)d_in[6];
  const float* Wv   = (const float*)d_in[7];
  const float* bv   = (const float*)d_in[8];
  const float* Wo   = (const float*)d_in[9];
  const float* bo   = (const float*)d_in[10];
  const float* ln2g = (const float*)d_in[11];
  const float* ln2b = (const float*)d_in[12];
  const float* W1   = (const float*)d_in[13];
  const float* b1   = (const float*)d_in[14];
  const float* W2   = (const float*)d_in[15];
  const float* b2   = (const float*)d_in[16];

  char* ws = (char*)d_ws;
  size_t off = 0;
  short* Wtqkv = (short*)(ws + off); off += (size_t)2304 * 768 * 2;
  short* Wto   = (short*)(ws + off); off += (size_t)768 * 768 * 2;
  short* Wt1   = (short*)(ws + off); off += (size_t)3072 * 768 * 2;
  short* Wt2   = (short*)(ws + off); off += (size_t)768 * 3072 * 2;
  float* bqkv  = (float*)(ws + off); off += 16384;
  short* hb    = (short*)(ws + off); off += (size_t)8192 * 768 * 2;
  short* qkv   = (short*)(ws + off); off += (size_t)8192 * 2304 * 2;
  short* h2b   = (short*)(ws + off); off += (size_t)8192 * 768 * 2;
  short* f1 = hb;          // [8192][3072] bf16, overlays hb+qkv (both dead)
  short* ab = hb;          // attention output overlays hb
  short* vT = h2b;         // V^T [64*96][1024], overlays h2b
  float* x1 = (float*)d_out;  // residual stream parked in d_out

  transpose_cvt<<<dim3(24, 24), 256, 0, stream>>>(Wq, Wtqkv, 768, 768);
  transpose_cvt<<<dim3(24, 24), 256, 0, stream>>>(Wk, Wtqkv + (size_t)768 * 768, 768, 768);
  transpose_cvt<<<dim3(24, 24), 256, 0, stream>>>(Wv, Wtqkv + (size_t)1536 * 768, 768, 768);
  transpose_cvt<<<dim3(24, 24), 256, 0, stream>>>(Wo, Wto, 768, 768);
  transpose_cvt<<<dim3(96, 24), 256, 0, stream>>>(W1, Wt1, 768, 3072);
  transpose_cvt<<<dim3(24, 96), 256, 0, stream>>>(W2, Wt2, 3072, 768);
  hipMemcpyAsync(bqkv,        bq, 768 * sizeof(float), hipMemcpyDeviceToDevice, stream);
  hipMemcpyAsync(bqkv + 768,  bk, 768 * sizeof(float), hipMemcpyDeviceToDevice, stream);
  hipMemcpyAsync(bqkv + 1536, bv, 768 * sizeof(float), hipMemcpyDeviceToDevice, stream);

  ln_rows<<<2048, 256, 0, stream>>>(x, ln1g, ln1b, (unsigned short*)hb);
  gemm_bt<EPI_BF16><<<64 * 18, 256, 0, stream>>>(hb, Wtqkv, bqkv, nullptr, qkv, 2304, 18, 768);
  v_transpose<<<dim3(64, 16), 256, 0, stream>>>(qkv, vT);
  attn_fwd<<<1024, 256, 0, stream>>>(qkv, vT, (unsigned short*)ab);
  gemm_bt<EPI_F32_RES><<<64 * 6, 256, 0, stream>>>(ab, Wto, bo, x, x1, 768, 6, 768);

  ln_rows<<<2048, 256, 0, stream>>>(x1, ln2g, ln2b, (unsigned short*)h2b);
  gemm_bt<EPI_BF16_GELU><<<64 * 24, 256, 0, stream>>>(h2b, Wt1, b1, nullptr, f1, 3072, 24, 768);
  gemm_bt<EPI_F32><<<64 * 6, 256, 0, stream>>>(f1, Wt2, b2, nullptr, (float*)d_out, 768, 6, 3072);
}